// Round 2
// 3128.253 us; speedup vs baseline: 1.7413x; 1.7413x over previous
//
#include <hip/hip_runtime.h>
#include <math.h>

// LSTM decoder, persistent design.
//   batch 256, input 512, hidden H=1024, T=256 steps, out (256,256,1024) fp32.
// Grid: 256 blocks = 2 batch-groups (mg, 128 samples) x 128 gate-slices (ng).
// W_hh slice (32 cols x 1024 k fp16 = 64 KB) resident in LDS all 256 steps.
//
// R7 = R6 + container-crash defenses:
//  * host checks ws_size before using the 1MB fp16 transport buffer; if the
//    workspace is too small we fall back to the PROVEN R5 kernel (fp32
//    transport through `out`, 1KB ws). R6's unchecked hbuf writes were the
//    only plausible kernel-side container-killer (OOB workspace write).
//  * bounded poll (~4M spins) in the new kernel: a liveness bug now shows up
//    as passed:false instead of a dead container.
// R6 design (unchanged): fp16 parity-double-buffered h transport in d_ws
// (flag>=t certifies readers of parity t&1 are done => 2-deep safe), producer
// converts h to fp16 ONCE, pair-packs via shfl_xor(1) -> 512 MALL atomics per
// block-step; consumer acquires (buffer_inv) after poll, then direct f16x8
// loads feed MFMA A-fragments (64 loads/wave/step, zero cvt, 8-deep pipeline);
// fp32 out writes are nontemporal and issued AFTER the flag publish.

typedef _Float16 fp16_t;
typedef _Float16 f16x8 __attribute__((ext_vector_type(8)));
typedef float    f32x4 __attribute__((ext_vector_type(4)));

#define HID   1024
#define SEQ   256
#define INF   512
#define PF    8      // h-load software pipeline depth (k-blocks)

#define MFMA(a, b, c) __builtin_amdgcn_mfma_f32_16x16x32_f16((a), (b), (c), 0, 0, 0)

__device__ __forceinline__ float sigm(float x) { return 1.0f / (1.0f + __expf(-x)); }
__device__ __forceinline__ float tanh_fast(float x) { return 1.0f - 2.0f / (__expf(2.0f * x) + 1.0f); }

__device__ __forceinline__ f16x8 cvt8(float4 lo, float4 hi) {
    f16x8 v;
    v[0] = (fp16_t)lo.x; v[1] = (fp16_t)lo.y; v[2] = (fp16_t)lo.z; v[3] = (fp16_t)lo.w;
    v[4] = (fp16_t)hi.x; v[5] = (fp16_t)hi.y; v[6] = (fp16_t)hi.z; v[7] = (fp16_t)hi.w;
    return v;
}

// ---------------------------------------------------------------------------
// R6 kernel: fp16 transport in workspace
// ---------------------------------------------------------------------------
__global__ __launch_bounds__(256, 1) void lstm_persist_f16(
    const float* __restrict__ ctx,   // 256 x 512
    const float* __restrict__ wih,   // 4096 x 512
    const float* __restrict__ whh,   // 4096 x 1024
    const float* __restrict__ bih,   // 4096
    const float* __restrict__ bhh,   // 4096
    float* __restrict__ out,         // 256 x 256 x 1024 (write-only)
    unsigned int* __restrict__ flags,// 256 (zeroed before launch)
    fp16_t* __restrict__ hbuf)       // 2 x 256 x 1024 fp16 transport (parity)
{
    __shared__ __align__(16) fp16_t wlds[32 * HID];

    const int tid  = threadIdx.x;
    const int lane = tid & 63;
    const int wid  = tid >> 6;        // wave 0..3 -> 32-sample slice
    const int bid  = blockIdx.x;
    const int mg   = bid >> 7;        // 0..1   (128-sample group)
    const int ng   = bid & 127;       // 0..127 (8 hidden units)
    const int cl   = lane & 15;       // col within 16x16 tile
    const int q    = lane >> 4;       // k-quad 0..3
    const int hi   = (cl >> 3) & 1;   // 0: lane owns i,g ; 1: owns f,o
    const int nx   = cl & 7;          // swizzle key
    const int rot  = ng & 31;         // per-block k-rotation (spread MALL slices)
    const int odd  = lane & 1;

    // ---- one-time: stage W_hh slice into LDS as fp16, granule-swizzled ----
    for (int Gi = tid; Gi < 32 * 128; Gi += 256) {
        const int n = Gi >> 7, g = Gi & 127;
        const int grow = ((n >> 3) << 10) + (ng << 3) + (n & 7);
        const float4* src = reinterpret_cast<const float4*>(whh + (size_t)grow * HID + g * 8);
        float4 u0 = src[0], u1 = src[1];
        reinterpret_cast<f16x8*>(wlds)[n * 128 + (g ^ (n & 7))] = cvt8(u0, u1);
    }

    // ---- one-time: x_proj slice (= ctx @ w_ih^T + b_ih + b_hh) ----
    const int rowA0 = mg * 128 + wid * 32 + cl;  // mi=0 sample row
    const int rowA1 = rowA0 + 16;                // mi=1
    const int n0 = cl, n1 = 16 + cl;
    const int grow0 = ((n0 >> 3) << 10) + (ng << 3) + (n0 & 7);
    const int grow1 = ((n1 >> 3) << 10) + (ng << 3) + (n1 & 7);

    f32x4 x00 = {0.f, 0.f, 0.f, 0.f}, x01 = x00, x10 = x00, x11 = x00;
    {
        const float4* ca0 = reinterpret_cast<const float4*>(ctx + (size_t)rowA0 * INF);
        const float4* ca1 = reinterpret_cast<const float4*>(ctx + (size_t)rowA1 * INF);
        const float4* wb0 = reinterpret_cast<const float4*>(wih + (size_t)grow0 * INF);
        const float4* wb1 = reinterpret_cast<const float4*>(wih + (size_t)grow1 * INF);
#pragma unroll 4
        for (int kb = 0; kb < 16; ++kb) {
            const int vi = kb * 8 + q * 2;
            f16x8 a0 = cvt8(ca0[vi], ca0[vi + 1]);
            f16x8 a1 = cvt8(ca1[vi], ca1[vi + 1]);
            f16x8 b0 = cvt8(wb0[vi], wb0[vi + 1]);
            f16x8 b1 = cvt8(wb1[vi], wb1[vi + 1]);
            x00 = MFMA(a0, b0, x00); x01 = MFMA(a0, b1, x01);
            x10 = MFMA(a1, b0, x10); x11 = MFMA(a1, b1, x11);
        }
        const float bias0 = bih[grow0] + bhh[grow0];
        const float bias1 = bih[grow1] + bhh[grow1];
#pragma unroll
        for (int r = 0; r < 4; ++r) {
            x00[r] += bias0; x10[r] += bias0;
            x01[r] += bias1; x11[r] += bias1;
        }
    }
    __syncthreads();  // LDS staging complete

    const f16x8* wv = reinterpret_cast<const f16x8*>(wlds);

    const int sampW = mg * 128 + wid * 32 + hi * 16 + q * 4;
    const int ug    = (ng << 3) + (cl & 7);

    f32x4 cst = {0.f, 0.f, 0.f, 0.f};  // c-state

    for (int t = 0; t < SEQ; ++t) {
        f32x4 a00 = x00, a01 = x01, a10 = x10, a11 = x11;

        if (t > 0) {
            // wave 0 polls the 128 flags of our batch-group (flags live in MALL)
            if (wid == 0) {
                const unsigned tgt = (unsigned)t;
                const unsigned* fb = flags + mg * 128;
                // bounded poll: a liveness bug fails absmax instead of
                // hanging the container (~4M spins >> worst honest wait)
                for (int spin = 0; spin < (1 << 22); ++spin) {
                    unsigned f0 = __hip_atomic_load(fb + lane,      __ATOMIC_RELAXED, __HIP_MEMORY_SCOPE_AGENT);
                    unsigned f1 = __hip_atomic_load(fb + 64 + lane, __ATOMIC_RELAXED, __HIP_MEMORY_SCOPE_AGENT);
                    if (__all((f0 >= tgt) && (f1 >= tgt))) break;
                    __builtin_amdgcn_s_sleep(1);
                }
                // acquire (agent): invalidate stale L1/L2 copies of the
                // parity-recycled transport lines; reloads see MALL-fresh h
                // and re-allocate in L2 for intra-XCD sharing.
                __builtin_amdgcn_fence(__ATOMIC_ACQUIRE, "agent");
            }
            __syncthreads();   // releases waves 1-3; orders loads after inval
            asm volatile("" ::: "memory");

            const size_t pbase = (size_t)(((t - 1) & 1) * 256);
            const f16x8* pa0 = reinterpret_cast<const f16x8*>(hbuf + ((pbase + rowA0) << 10));
            const f16x8* pa1 = reinterpret_cast<const f16x8*>(hbuf + ((pbase + rowA1) << 10));

            // 8-deep software pipeline over 32 k-blocks (rotated per block)
            f16x8 va0[PF], va1[PF];
#pragma unroll
            for (int i = 0; i < PF; ++i) {
                const int k = (i + rot) & 31;
                va0[i] = pa0[k * 4 + q];
                va1[i] = pa1[k * 4 + q];
            }
#pragma unroll
            for (int kb = 0; kb < 32; ++kb) {
                const int s = kb & (PF - 1);
                f16x8 A0 = va0[s], A1 = va1[s];
                if (kb < 32 - PF) {
                    const int k = (kb + PF + rot) & 31;
                    va0[s] = pa0[k * 4 + q];
                    va1[s] = pa1[k * 4 + q];
                }
                const int cur = (kb + rot) & 31;
                const int gs = ((cur << 2) + q) ^ nx;
                f16x8 vb0 = wv[(cl << 7) + gs];
                f16x8 vb1 = wv[(cl << 7) + gs + 2048];
                a00 = MFMA(A0, vb0, a00); a01 = MFMA(A0, vb1, a01);
                a10 = MFMA(A1, vb0, a10); a11 = MFMA(A1, vb1, a11);
            }
        }

        // ---- epilogue: pair-exchange gates, LSTM cell fp32 ----
        f32x4 e00, e01, e10, e11;
#pragma unroll
        for (int r = 0; r < 4; ++r) {
            e00[r] = __shfl_xor(a00[r], 8, 64);
            e01[r] = __shfl_xor(a01[r], 8, 64);
            e10[r] = __shfl_xor(a10[r], 8, 64);
            e11[r] = __shfl_xor(a11[r], 8, 64);
        }
        f32x4 iv = hi ? e10 : a00;
        f32x4 fv = hi ? a10 : e00;
        f32x4 gv = hi ? e11 : a01;
        f32x4 ov = hi ? a11 : e01;

        float    hhf[4];
        unsigned hu[4];
#pragma unroll
        for (int r = 0; r < 4; ++r) {
            float ii = sigm(iv[r]);
            float ff = sigm(fv[r]);
            float gg = tanh_fast(gv[r]);
            float oo = sigm(ov[r]);
            float cc = ff * cst[r] + ii * gg;
            cst[r] = cc;
            float hh = oo * tanh_fast(cc);
            hhf[r] = hh;
            fp16_t hf = (fp16_t)hh;   // single rounding point
            hu[r] = (unsigned)__builtin_bit_cast(unsigned short, hf);
        }

        // ---- publish fp16 h into parity transport buffer (MALL atomics) ----
        // lane pair (lane^1) packs cols (ug&~1, ug|1); even lane writes r=0,1
        // and odd lane r=2,3 -> 2 atomics/lane, 512/block (was 1024).
        fp16_t* hbw = hbuf + (((size_t)((t & 1) * 256 + sampW)) << 10) + (ug & ~1);
#pragma unroll
        for (int r = 0; r < 4; ++r) {
            unsigned pu = __shfl_xor(hu[r], 1, 64);
            if (((r >> 1) & 1) == odd) {
                unsigned packed = odd ? (pu | (hu[r] << 16)) : (hu[r] | (pu << 16));
                __hip_atomic_exchange(reinterpret_cast<unsigned*>(hbw + (size_t)r * HID),
                                      packed, __ATOMIC_RELAXED, __HIP_MEMORY_SCOPE_AGENT);
            }
        }

        __syncthreads();  // drains all waves' transport atomics before flag
        if (tid == 0)
            __hip_atomic_exchange(&flags[bid], (unsigned)(t + 1),
                                  __ATOMIC_RELAXED, __HIP_MEMORY_SCOPE_AGENT);

        // ---- fp32 out writes: off the critical path, after the flag ----
        float* op = out + ((size_t)sampW * SEQ + t) * HID + ug;
#pragma unroll
        for (int r = 0; r < 4; ++r)
            __builtin_nontemporal_store(hhf[r], op + (size_t)r * SEQ * HID);
    }
}

// ---------------------------------------------------------------------------
// R5 fallback kernel (proven 5447us): fp32 transport through `out`, 1KB ws
// ---------------------------------------------------------------------------
__global__ __launch_bounds__(256, 1) void lstm_persist_f32(
    const float* __restrict__ ctx,
    const float* __restrict__ wih,
    const float* __restrict__ whh,
    const float* __restrict__ bih,
    const float* __restrict__ bhh,
    float* __restrict__ out,
    unsigned int* __restrict__ flags)
{
    __shared__ __align__(16) fp16_t wlds[32 * HID];

    const int tid  = threadIdx.x;
    const int lane = tid & 63;
    const int wid  = tid >> 6;
    const int bid  = blockIdx.x;
    const int mg   = bid >> 7;
    const int ng   = bid & 127;
    const int cl   = lane & 15;
    const int q    = lane >> 4;
    const int hi   = (cl >> 3) & 1;
    const int nx   = cl & 7;
    const int rot  = ng & 31;

    for (int Gi = tid; Gi < 32 * 128; Gi += 256) {
        const int n = Gi >> 7, g = Gi & 127;
        const int grow = ((n >> 3) << 10) + (ng << 3) + (n & 7);
        const float4* src = reinterpret_cast<const float4*>(whh + (size_t)grow * HID + g * 8);
        float4 u0 = src[0], u1 = src[1];
        reinterpret_cast<f16x8*>(wlds)[n * 128 + (g ^ (n & 7))] = cvt8(u0, u1);
    }

    const int rowA0 = mg * 128 + wid * 32 + cl;
    const int rowA1 = rowA0 + 16;
    const int n0 = cl, n1 = 16 + cl;
    const int grow0 = ((n0 >> 3) << 10) + (ng << 3) + (n0 & 7);
    const int grow1 = ((n1 >> 3) << 10) + (ng << 3) + (n1 & 7);

    f32x4 x00 = {0.f, 0.f, 0.f, 0.f}, x01 = x00, x10 = x00, x11 = x00;
    {
        const float4* ca0 = reinterpret_cast<const float4*>(ctx + (size_t)rowA0 * INF);
        const float4* ca1 = reinterpret_cast<const float4*>(ctx + (size_t)rowA1 * INF);
        const float4* wb0 = reinterpret_cast<const float4*>(wih + (size_t)grow0 * INF);
        const float4* wb1 = reinterpret_cast<const float4*>(wih + (size_t)grow1 * INF);
#pragma unroll 4
        for (int kb = 0; kb < 16; ++kb) {
            const int vi = kb * 8 + q * 2;
            f16x8 a0 = cvt8(ca0[vi], ca0[vi + 1]);
            f16x8 a1 = cvt8(ca1[vi], ca1[vi + 1]);
            f16x8 b0 = cvt8(wb0[vi], wb0[vi + 1]);
            f16x8 b1 = cvt8(wb1[vi], wb1[vi + 1]);
            x00 = MFMA(a0, b0, x00); x01 = MFMA(a0, b1, x01);
            x10 = MFMA(a1, b0, x10); x11 = MFMA(a1, b1, x11);
        }
        const float bias0 = bih[grow0] + bhh[grow0];
        const float bias1 = bih[grow1] + bhh[grow1];
#pragma unroll
        for (int r = 0; r < 4; ++r) {
            x00[r] += bias0; x10[r] += bias0;
            x01[r] += bias1; x11[r] += bias1;
        }
    }
    __syncthreads();

    const f16x8* wv = reinterpret_cast<const f16x8*>(wlds);
    const int sampW = mg * 128 + wid * 32 + hi * 16 + q * 4;
    const int ug    = (ng << 3) + (cl & 7);

    f32x4 cst = {0.f, 0.f, 0.f, 0.f};

    for (int t = 0; t < SEQ; ++t) {
        f32x4 a00 = x00, a01 = x01, a10 = x10, a11 = x11;

        if (t > 0) {
            if (wid == 0) {
                const unsigned tgt = (unsigned)t;
                const unsigned* fb = flags + mg * 128;
                for (;;) {
                    unsigned f0 = __hip_atomic_load(fb + lane,      __ATOMIC_RELAXED, __HIP_MEMORY_SCOPE_AGENT);
                    unsigned f1 = __hip_atomic_load(fb + 64 + lane, __ATOMIC_RELAXED, __HIP_MEMORY_SCOPE_AGENT);
                    if (__all((f0 >= tgt) && (f1 >= tgt))) break;
                    __builtin_amdgcn_s_sleep(1);
                }
            }
            __syncthreads();
            asm volatile("" ::: "memory");

            const float4* pa0 = reinterpret_cast<const float4*>(out + ((size_t)rowA0 * SEQ + (t - 1)) * HID);
            const float4* pa1 = reinterpret_cast<const float4*>(out + ((size_t)rowA1 * SEQ + (t - 1)) * HID);

            int cur = rot;
            float4 c00 = pa0[cur * 8 + q * 2], c01 = pa0[cur * 8 + q * 2 + 1];
            float4 c10 = pa1[cur * 8 + q * 2], c11 = pa1[cur * 8 + q * 2 + 1];
#pragma unroll 8
            for (int kb = 0; kb < 32; ++kb) {
                float4 d00, d01, d10, d11;
                if (kb < 31) {
                    const int nxt = (kb + 1 + rot) & 31;
                    d00 = pa0[nxt * 8 + q * 2]; d01 = pa0[nxt * 8 + q * 2 + 1];
                    d10 = pa1[nxt * 8 + q * 2]; d11 = pa1[nxt * 8 + q * 2 + 1];
                }
                f16x8 va0 = cvt8(c00, c01);
                f16x8 va1 = cvt8(c10, c11);
                const int gs = ((cur << 2) + q) ^ nx;
                f16x8 vb0 = wv[(cl << 7) + gs];
                f16x8 vb1 = wv[(cl << 7) + gs + 2048];
                a00 = MFMA(va0, vb0, a00); a01 = MFMA(va0, vb1, a01);
                a10 = MFMA(va1, vb0, a10); a11 = MFMA(va1, vb1, a11);
                c00 = d00; c01 = d01; c10 = d10; c11 = d11;
                cur = (kb + 1 + rot) & 31;
            }
        }

        f32x4 e00, e01, e10, e11;
#pragma unroll
        for (int r = 0; r < 4; ++r) {
            e00[r] = __shfl_xor(a00[r], 8, 64);
            e01[r] = __shfl_xor(a01[r], 8, 64);
            e10[r] = __shfl_xor(a10[r], 8, 64);
            e11[r] = __shfl_xor(a11[r], 8, 64);
        }
        f32x4 iv = hi ? e10 : a00;
        f32x4 fv = hi ? a10 : e00;
        f32x4 gv = hi ? e11 : a01;
        f32x4 ov = hi ? a11 : e01;

        unsigned* ow = reinterpret_cast<unsigned*>(out + ((size_t)sampW * SEQ + t) * HID + ug);
#pragma unroll
        for (int r = 0; r < 4; ++r) {
            float ii = sigm(iv[r]);
            float ff = sigm(fv[r]);
            float gg = tanh_fast(gv[r]);
            float oo = sigm(ov[r]);
            float cc = ff * cst[r] + ii * gg;
            cst[r] = cc;
            float hh = oo * tanh_fast(cc);
            __hip_atomic_exchange(ow + (size_t)r * SEQ * HID,
                                  __builtin_bit_cast(unsigned, hh),
                                  __ATOMIC_RELAXED, __HIP_MEMORY_SCOPE_AGENT);
        }

        __syncthreads();
        if (tid == 0)
            __hip_atomic_exchange(&flags[bid], (unsigned)(t + 1),
                                  __ATOMIC_RELAXED, __HIP_MEMORY_SCOPE_AGENT);
    }
}

extern "C" void kernel_launch(void* const* d_in, const int* in_sizes, int n_in,
                              void* d_out, int out_size, void* d_ws, size_t ws_size,
                              hipStream_t stream) {
    const float* ctx = (const float*)d_in[0];
    const float* wih = (const float*)d_in[1];
    const float* whh = (const float*)d_in[2];
    const float* bih = (const float*)d_in[3];
    const float* bhh = (const float*)d_in[4];
    float* out = (float*)d_out;

    unsigned int* flags = (unsigned int*)d_ws;
    hipMemsetAsync(d_ws, 0, 1024, stream);      // zero flags only

    const size_t need = 1024 + (size_t)2 * 256 * 1024 * sizeof(fp16_t);
    if (ws_size >= need) {
        fp16_t* hbuf = (fp16_t*)((char*)d_ws + 1024);
        lstm_persist_f16<<<dim3(256), dim3(256), 0, stream>>>(ctx, wih, whh, bih, bhh,
                                                              out, flags, hbuf);
    } else {
        lstm_persist_f32<<<dim3(256), dim3(256), 0, stream>>>(ctx, wih, whh, bih, bhh,
                                                              out, flags);
    }
}

// Round 3
// 2745.990 us; speedup vs baseline: 1.9837x; 1.1392x over previous
//
#include <hip/hip_runtime.h>
#include <math.h>

// LSTM decoder, persistent design.
//   batch 256, input 512, hidden H=1024, T=256 steps, out (256,256,1024) fp32.
// Grid: 256 blocks = 2 batch-groups (mg, 128 samples) x 128 gate-slices (ng).
// W_hh slice (32 cols x 1024 k fp16 = 64 KB) resident in LDS all 256 steps.
//
// R8: kill the per-step agent-acquire fence (buffer_inv nukes the whole
// per-XCD L2 -> no intra-XCD sharing of the h broadcast -> 64 MB/step
// streamed from MALL). Transport becomes WRITE-ONCE (indexed by t, 134 MB)
// when the workspace allows: addresses never recycle, so normal cached
// loads are safe with NO fence (the proven R4/R5 property), and co-XCD
// blocks share h lines in L2 (~512 KB unique/XCD/step instead of 8 MB).
// Fallback chain: write-once (tmask=255, fence=0) -> parity 2-buffer
// (tmask=1, fence=1; the measured 3128 us config) -> R5 fp32-in-out.
// Publish stays relaxed agent-scope atomic-exchange: RMW executes at the
// MALL, so h allocates MALL-dirty (consumer misses hit MALL, not DRAM).

typedef _Float16 fp16_t;
typedef _Float16 f16x8 __attribute__((ext_vector_type(8)));
typedef float    f32x4 __attribute__((ext_vector_type(4)));

#define HID   1024
#define SEQ   256
#define INF   512
#define PF    8      // h-load software pipeline depth (k-blocks)

#define MFMA(a, b, c) __builtin_amdgcn_mfma_f32_16x16x32_f16((a), (b), (c), 0, 0, 0)

__device__ __forceinline__ float sigm(float x) { return 1.0f / (1.0f + __expf(-x)); }
__device__ __forceinline__ float tanh_fast(float x) { return 1.0f - 2.0f / (__expf(2.0f * x) + 1.0f); }

__device__ __forceinline__ f16x8 cvt8(float4 lo, float4 hi) {
    f16x8 v;
    v[0] = (fp16_t)lo.x; v[1] = (fp16_t)lo.y; v[2] = (fp16_t)lo.z; v[3] = (fp16_t)lo.w;
    v[4] = (fp16_t)hi.x; v[5] = (fp16_t)hi.y; v[6] = (fp16_t)hi.z; v[7] = (fp16_t)hi.w;
    return v;
}

// ---------------------------------------------------------------------------
// fp16-transport kernel. tmask selects buffering:
//   tmask=255 : write-once (slot = t), no fence needed   (do_fence=0)
//   tmask=1   : parity double-buffer (slot = t&1), fence (do_fence=1)
// ---------------------------------------------------------------------------
__global__ __launch_bounds__(256, 1) void lstm_persist_f16(
    const float* __restrict__ ctx,   // 256 x 512
    const float* __restrict__ wih,   // 4096 x 512
    const float* __restrict__ whh,   // 4096 x 1024
    const float* __restrict__ bih,   // 4096
    const float* __restrict__ bhh,   // 4096
    float* __restrict__ out,         // 256 x 256 x 1024 (write-only)
    unsigned int* __restrict__ flags,// 256 (zeroed before launch)
    fp16_t* __restrict__ hbuf,       // (tmask+1) x 256 x 1024 fp16 transport
    const int tmask, const int do_fence)
{
    __shared__ __align__(16) fp16_t wlds[32 * HID];

    const int tid  = threadIdx.x;
    const int lane = tid & 63;
    const int wid  = tid >> 6;        // wave 0..3 -> 32-sample slice
    const int bid  = blockIdx.x;
    const int mg   = bid >> 7;        // 0..1   (128-sample group)
    const int ng   = bid & 127;       // 0..127 (8 hidden units)
    const int cl   = lane & 15;       // col within 16x16 tile
    const int q    = lane >> 4;       // k-quad 0..3
    const int hi   = (cl >> 3) & 1;   // 0: lane owns i,g ; 1: owns f,o
    const int nx   = cl & 7;          // swizzle key
    const int rot  = ng & 31;         // per-block k-rotation (spread MALL slices)
    const int odd  = lane & 1;

    // ---- one-time: stage W_hh slice into LDS as fp16, granule-swizzled ----
    for (int Gi = tid; Gi < 32 * 128; Gi += 256) {
        const int n = Gi >> 7, g = Gi & 127;
        const int grow = ((n >> 3) << 10) + (ng << 3) + (n & 7);
        const float4* src = reinterpret_cast<const float4*>(whh + (size_t)grow * HID + g * 8);
        float4 u0 = src[0], u1 = src[1];
        reinterpret_cast<f16x8*>(wlds)[n * 128 + (g ^ (n & 7))] = cvt8(u0, u1);
    }

    // ---- one-time: x_proj slice (= ctx @ w_ih^T + b_ih + b_hh) ----
    const int rowA0 = mg * 128 + wid * 32 + cl;  // mi=0 sample row
    const int rowA1 = rowA0 + 16;                // mi=1
    const int n0 = cl, n1 = 16 + cl;
    const int grow0 = ((n0 >> 3) << 10) + (ng << 3) + (n0 & 7);
    const int grow1 = ((n1 >> 3) << 10) + (ng << 3) + (n1 & 7);

    f32x4 x00 = {0.f, 0.f, 0.f, 0.f}, x01 = x00, x10 = x00, x11 = x00;
    {
        const float4* ca0 = reinterpret_cast<const float4*>(ctx + (size_t)rowA0 * INF);
        const float4* ca1 = reinterpret_cast<const float4*>(ctx + (size_t)rowA1 * INF);
        const float4* wb0 = reinterpret_cast<const float4*>(wih + (size_t)grow0 * INF);
        const float4* wb1 = reinterpret_cast<const float4*>(wih + (size_t)grow1 * INF);
#pragma unroll 4
        for (int kb = 0; kb < 16; ++kb) {
            const int vi = kb * 8 + q * 2;
            f16x8 a0 = cvt8(ca0[vi], ca0[vi + 1]);
            f16x8 a1 = cvt8(ca1[vi], ca1[vi + 1]);
            f16x8 b0 = cvt8(wb0[vi], wb0[vi + 1]);
            f16x8 b1 = cvt8(wb1[vi], wb1[vi + 1]);
            x00 = MFMA(a0, b0, x00); x01 = MFMA(a0, b1, x01);
            x10 = MFMA(a1, b0, x10); x11 = MFMA(a1, b1, x11);
        }
        const float bias0 = bih[grow0] + bhh[grow0];
        const float bias1 = bih[grow1] + bhh[grow1];
#pragma unroll
        for (int r = 0; r < 4; ++r) {
            x00[r] += bias0; x10[r] += bias0;
            x01[r] += bias1; x11[r] += bias1;
        }
    }
    __syncthreads();  // LDS staging complete

    const f16x8* wv = reinterpret_cast<const f16x8*>(wlds);

    const int sampW = mg * 128 + wid * 32 + hi * 16 + q * 4;
    const int ug    = (ng << 3) + (cl & 7);

    f32x4 cst = {0.f, 0.f, 0.f, 0.f};  // c-state

    for (int t = 0; t < SEQ; ++t) {
        f32x4 a00 = x00, a01 = x01, a10 = x10, a11 = x11;

        if (t > 0) {
            // wave 0 polls the 128 flags of our batch-group (flags live in MALL)
            if (wid == 0) {
                const unsigned tgt = (unsigned)t;
                const unsigned* fb = flags + mg * 128;
                // bounded poll: a liveness bug fails absmax instead of
                // hanging the container (~4M spins >> worst honest wait)
                for (int spin = 0; spin < (1 << 22); ++spin) {
                    unsigned f0 = __hip_atomic_load(fb + lane,      __ATOMIC_RELAXED, __HIP_MEMORY_SCOPE_AGENT);
                    unsigned f1 = __hip_atomic_load(fb + 64 + lane, __ATOMIC_RELAXED, __HIP_MEMORY_SCOPE_AGENT);
                    if (__all((f0 >= tgt) && (f1 >= tgt))) break;
                    __builtin_amdgcn_s_sleep(1);
                }
                // parity mode only: transport addresses recycle every 2 steps,
                // so stale L1/L2 lines must be invalidated (agent acquire ->
                // buffer_inv). Write-once mode needs NO fence: addresses are
                // virgin, normal cached loads see MALL-fresh data and co-XCD
                // blocks share the lines in L2.
                if (do_fence)
                    __builtin_amdgcn_fence(__ATOMIC_ACQUIRE, "agent");
            }
            __syncthreads();   // releases waves 1-3; orders loads after poll
            asm volatile("" ::: "memory");

            const size_t pbase = (size_t)(((t - 1) & tmask) * 256);
            const f16x8* pa0 = reinterpret_cast<const f16x8*>(hbuf + ((pbase + rowA0) << 10));
            const f16x8* pa1 = reinterpret_cast<const f16x8*>(hbuf + ((pbase + rowA1) << 10));

            // 8-deep software pipeline over 32 k-blocks (rotated per block)
            f16x8 va0[PF], va1[PF];
#pragma unroll
            for (int i = 0; i < PF; ++i) {
                const int k = (i + rot) & 31;
                va0[i] = pa0[k * 4 + q];
                va1[i] = pa1[k * 4 + q];
            }
#pragma unroll
            for (int kb = 0; kb < 32; ++kb) {
                const int s = kb & (PF - 1);
                f16x8 A0 = va0[s], A1 = va1[s];
                if (kb < 32 - PF) {
                    const int k = (kb + PF + rot) & 31;
                    va0[s] = pa0[k * 4 + q];
                    va1[s] = pa1[k * 4 + q];
                }
                const int cur = (kb + rot) & 31;
                const int gs = ((cur << 2) + q) ^ nx;
                f16x8 vb0 = wv[(cl << 7) + gs];
                f16x8 vb1 = wv[(cl << 7) + gs + 2048];
                a00 = MFMA(A0, vb0, a00); a01 = MFMA(A0, vb1, a01);
                a10 = MFMA(A1, vb0, a10); a11 = MFMA(A1, vb1, a11);
            }
        }

        // ---- epilogue: pair-exchange gates, LSTM cell fp32 ----
        f32x4 e00, e01, e10, e11;
#pragma unroll
        for (int r = 0; r < 4; ++r) {
            e00[r] = __shfl_xor(a00[r], 8, 64);
            e01[r] = __shfl_xor(a01[r], 8, 64);
            e10[r] = __shfl_xor(a10[r], 8, 64);
            e11[r] = __shfl_xor(a11[r], 8, 64);
        }
        f32x4 iv = hi ? e10 : a00;
        f32x4 fv = hi ? a10 : e00;
        f32x4 gv = hi ? e11 : a01;
        f32x4 ov = hi ? a11 : e01;

        float    hhf[4];
        unsigned hu[4];
#pragma unroll
        for (int r = 0; r < 4; ++r) {
            float ii = sigm(iv[r]);
            float ff = sigm(fv[r]);
            float gg = tanh_fast(gv[r]);
            float oo = sigm(ov[r]);
            float cc = ff * cst[r] + ii * gg;
            cst[r] = cc;
            float hh = oo * tanh_fast(cc);
            hhf[r] = hh;
            fp16_t hf = (fp16_t)hh;   // single rounding point
            hu[r] = (unsigned)__builtin_bit_cast(unsigned short, hf);
        }

        // ---- publish fp16 h into transport slot (MALL atomics) ----
        // lane pair (lane^1) packs cols (ug&~1, ug|1); even lane writes r=0,1
        // and odd lane r=2,3 -> 2 atomics/lane, 512/block.
        fp16_t* hbw = hbuf + (((size_t)((t & tmask) * 256 + sampW)) << 10) + (ug & ~1);
#pragma unroll
        for (int r = 0; r < 4; ++r) {
            unsigned pu = __shfl_xor(hu[r], 1, 64);
            if (((r >> 1) & 1) == odd) {
                unsigned packed = odd ? (pu | (hu[r] << 16)) : (hu[r] | (pu << 16));
                __hip_atomic_exchange(reinterpret_cast<unsigned*>(hbw + (size_t)r * HID),
                                      packed, __ATOMIC_RELAXED, __HIP_MEMORY_SCOPE_AGENT);
            }
        }

        __syncthreads();  // drains all waves' transport atomics before flag
        if (tid == 0)
            __hip_atomic_exchange(&flags[bid], (unsigned)(t + 1),
                                  __ATOMIC_RELAXED, __HIP_MEMORY_SCOPE_AGENT);

        // ---- fp32 out writes: off the critical path, after the flag ----
        float* op = out + ((size_t)sampW * SEQ + t) * HID + ug;
#pragma unroll
        for (int r = 0; r < 4; ++r)
            __builtin_nontemporal_store(hhf[r], op + (size_t)r * SEQ * HID);
    }
}

// ---------------------------------------------------------------------------
// R5 fallback kernel (proven 5447us): fp32 transport through `out`, 1KB ws
// ---------------------------------------------------------------------------
__global__ __launch_bounds__(256, 1) void lstm_persist_f32(
    const float* __restrict__ ctx,
    const float* __restrict__ wih,
    const float* __restrict__ whh,
    const float* __restrict__ bih,
    const float* __restrict__ bhh,
    float* __restrict__ out,
    unsigned int* __restrict__ flags)
{
    __shared__ __align__(16) fp16_t wlds[32 * HID];

    const int tid  = threadIdx.x;
    const int lane = tid & 63;
    const int wid  = tid >> 6;
    const int bid  = blockIdx.x;
    const int mg   = bid >> 7;
    const int ng   = bid & 127;
    const int cl   = lane & 15;
    const int q    = lane >> 4;
    const int hi   = (cl >> 3) & 1;
    const int nx   = cl & 7;
    const int rot  = ng & 31;

    for (int Gi = tid; Gi < 32 * 128; Gi += 256) {
        const int n = Gi >> 7, g = Gi & 127;
        const int grow = ((n >> 3) << 10) + (ng << 3) + (n & 7);
        const float4* src = reinterpret_cast<const float4*>(whh + (size_t)grow * HID + g * 8);
        float4 u0 = src[0], u1 = src[1];
        reinterpret_cast<f16x8*>(wlds)[n * 128 + (g ^ (n & 7))] = cvt8(u0, u1);
    }

    const int rowA0 = mg * 128 + wid * 32 + cl;
    const int rowA1 = rowA0 + 16;
    const int n0 = cl, n1 = 16 + cl;
    const int grow0 = ((n0 >> 3) << 10) + (ng << 3) + (n0 & 7);
    const int grow1 = ((n1 >> 3) << 10) + (ng << 3) + (n1 & 7);

    f32x4 x00 = {0.f, 0.f, 0.f, 0.f}, x01 = x00, x10 = x00, x11 = x00;
    {
        const float4* ca0 = reinterpret_cast<const float4*>(ctx + (size_t)rowA0 * INF);
        const float4* ca1 = reinterpret_cast<const float4*>(ctx + (size_t)rowA1 * INF);
        const float4* wb0 = reinterpret_cast<const float4*>(wih + (size_t)grow0 * INF);
        const float4* wb1 = reinterpret_cast<const float4*>(wih + (size_t)grow1 * INF);
#pragma unroll 4
        for (int kb = 0; kb < 16; ++kb) {
            const int vi = kb * 8 + q * 2;
            f16x8 a0 = cvt8(ca0[vi], ca0[vi + 1]);
            f16x8 a1 = cvt8(ca1[vi], ca1[vi + 1]);
            f16x8 b0 = cvt8(wb0[vi], wb0[vi + 1]);
            f16x8 b1 = cvt8(wb1[vi], wb1[vi + 1]);
            x00 = MFMA(a0, b0, x00); x01 = MFMA(a0, b1, x01);
            x10 = MFMA(a1, b0, x10); x11 = MFMA(a1, b1, x11);
        }
        const float bias0 = bih[grow0] + bhh[grow0];
        const float bias1 = bih[grow1] + bhh[grow1];
#pragma unroll
        for (int r = 0; r < 4; ++r) {
            x00[r] += bias0; x10[r] += bias0;
            x01[r] += bias1; x11[r] += bias1;
        }
    }
    __syncthreads();

    const f16x8* wv = reinterpret_cast<const f16x8*>(wlds);
    const int sampW = mg * 128 + wid * 32 + hi * 16 + q * 4;
    const int ug    = (ng << 3) + (cl & 7);

    f32x4 cst = {0.f, 0.f, 0.f, 0.f};

    for (int t = 0; t < SEQ; ++t) {
        f32x4 a00 = x00, a01 = x01, a10 = x10, a11 = x11;

        if (t > 0) {
            if (wid == 0) {
                const unsigned tgt = (unsigned)t;
                const unsigned* fb = flags + mg * 128;
                for (;;) {
                    unsigned f0 = __hip_atomic_load(fb + lane,      __ATOMIC_RELAXED, __HIP_MEMORY_SCOPE_AGENT);
                    unsigned f1 = __hip_atomic_load(fb + 64 + lane, __ATOMIC_RELAXED, __HIP_MEMORY_SCOPE_AGENT);
                    if (__all((f0 >= tgt) && (f1 >= tgt))) break;
                    __builtin_amdgcn_s_sleep(1);
                }
            }
            __syncthreads();
            asm volatile("" ::: "memory");

            const float4* pa0 = reinterpret_cast<const float4*>(out + ((size_t)rowA0 * SEQ + (t - 1)) * HID);
            const float4* pa1 = reinterpret_cast<const float4*>(out + ((size_t)rowA1 * SEQ + (t - 1)) * HID);

            int cur = rot;
            float4 c00 = pa0[cur * 8 + q * 2], c01 = pa0[cur * 8 + q * 2 + 1];
            float4 c10 = pa1[cur * 8 + q * 2], c11 = pa1[cur * 8 + q * 2 + 1];
#pragma unroll 8
            for (int kb = 0; kb < 32; ++kb) {
                float4 d00, d01, d10, d11;
                if (kb < 31) {
                    const int nxt = (kb + 1 + rot) & 31;
                    d00 = pa0[nxt * 8 + q * 2]; d01 = pa0[nxt * 8 + q * 2 + 1];
                    d10 = pa1[nxt * 8 + q * 2]; d11 = pa1[nxt * 8 + q * 2 + 1];
                }
                f16x8 va0 = cvt8(c00, c01);
                f16x8 va1 = cvt8(c10, c11);
                const int gs = ((cur << 2) + q) ^ nx;
                f16x8 vb0 = wv[(cl << 7) + gs];
                f16x8 vb1 = wv[(cl << 7) + gs + 2048];
                a00 = MFMA(va0, vb0, a00); a01 = MFMA(va0, vb1, a01);
                a10 = MFMA(va1, vb0, a10); a11 = MFMA(va1, vb1, a11);
                c00 = d00; c01 = d01; c10 = d10; c11 = d11;
                cur = (kb + 1 + rot) & 31;
            }
        }

        f32x4 e00, e01, e10, e11;
#pragma unroll
        for (int r = 0; r < 4; ++r) {
            e00[r] = __shfl_xor(a00[r], 8, 64);
            e01[r] = __shfl_xor(a01[r], 8, 64);
            e10[r] = __shfl_xor(a10[r], 8, 64);
            e11[r] = __shfl_xor(a11[r], 8, 64);
        }
        f32x4 iv = hi ? e10 : a00;
        f32x4 fv = hi ? a10 : e00;
        f32x4 gv = hi ? e11 : a01;
        f32x4 ov = hi ? a11 : e01;

        unsigned* ow = reinterpret_cast<unsigned*>(out + ((size_t)sampW * SEQ + t) * HID + ug);
#pragma unroll
        for (int r = 0; r < 4; ++r) {
            float ii = sigm(iv[r]);
            float ff = sigm(fv[r]);
            float gg = tanh_fast(gv[r]);
            float oo = sigm(ov[r]);
            float cc = ff * cst[r] + ii * gg;
            cst[r] = cc;
            float hh = oo * tanh_fast(cc);
            __hip_atomic_exchange(ow + (size_t)r * SEQ * HID,
                                  __builtin_bit_cast(unsigned, hh),
                                  __ATOMIC_RELAXED, __HIP_MEMORY_SCOPE_AGENT);
        }

        __syncthreads();
        if (tid == 0)
            __hip_atomic_exchange(&flags[bid], (unsigned)(t + 1),
                                  __ATOMIC_RELAXED, __HIP_MEMORY_SCOPE_AGENT);
    }
}

extern "C" void kernel_launch(void* const* d_in, const int* in_sizes, int n_in,
                              void* d_out, int out_size, void* d_ws, size_t ws_size,
                              hipStream_t stream) {
    const float* ctx = (const float*)d_in[0];
    const float* wih = (const float*)d_in[1];
    const float* whh = (const float*)d_in[2];
    const float* bih = (const float*)d_in[3];
    const float* bhh = (const float*)d_in[4];
    float* out = (float*)d_out;

    unsigned int* flags = (unsigned int*)d_ws;
    hipMemsetAsync(d_ws, 0, 1024, stream);      // zero flags only

    const size_t need_once   = 1024 + (size_t)SEQ * 256 * 1024 * sizeof(fp16_t); // ~134 MB
    const size_t need_parity = 1024 + (size_t)2   * 256 * 1024 * sizeof(fp16_t); // ~1 MB
    if (ws_size >= need_once) {
        // write-once transport: no fence, L2-shared h broadcast
        fp16_t* hbuf = (fp16_t*)((char*)d_ws + 1024);
        lstm_persist_f16<<<dim3(256), dim3(256), 0, stream>>>(ctx, wih, whh, bih, bhh,
                                                              out, flags, hbuf,
                                                              /*tmask=*/SEQ - 1, /*fence=*/0);
    } else if (ws_size >= need_parity) {
        // parity double-buffer (R7 measured config)
        fp16_t* hbuf = (fp16_t*)((char*)d_ws + 1024);
        lstm_persist_f16<<<dim3(256), dim3(256), 0, stream>>>(ctx, wih, whh, bih, bhh,
                                                              out, flags, hbuf,
                                                              /*tmask=*/1, /*fence=*/1);
    } else {
        lstm_persist_f32<<<dim3(256), dim3(256), 0, stream>>>(ctx, wih, whh, bih, bhh,
                                                              out, flags);
    }
}